// Round 11
// baseline (344.575 us; speedup 1.0000x reference)
//
#include <hip/hip_runtime.h>

#define BN 4096
#define BD 128
#define NB 4
#define TOPK 20
#define CAND 96
#define EPS_U 0.9f              // unscaled-score margin (covers MFMA + bf16-storage err, >=11 sigma)

typedef float f32x16 __attribute__((ext_vector_type(16)));
typedef short bf16x8 __attribute__((ext_vector_type(8)));

__device__ inline unsigned short f2bf(float f) {
  unsigned int u = __float_as_uint(f);
  unsigned int r = (u + 0x7FFFu + ((u >> 16) & 1u)) >> 16;
  return (unsigned short)r;
}

// ---------------- Projection (f64 accumulate) -> Qd, Kd (f64) + Khi (bf16) ----------------
__global__ __launch_bounds__(256) void proj_kernel(
    const float* __restrict__ x,
    const float* __restrict__ Wq, const float* __restrict__ bq,
    const float* __restrict__ Wk, const float* __restrict__ bk,
    double* __restrict__ Qd, double* __restrict__ Kd, unsigned short* __restrict__ Khi) {
  __shared__ double xs[32][129];
  const int tid = threadIdx.x;
  const long row0 = (long)blockIdx.x * 32;
  const float* xsrc = x + row0 * BD;
  for (int i = tid; i < 32 * BD; i += 256) xs[i >> 7][i & 127] = (double)xsrc[i];
  __syncthreads();

  const int e = tid & 127;
  const bool isK = tid >= 128;
  const float* W = isK ? Wk : Wq;
  const float* bias = isK ? bk : bq;
  double* Od = isK ? Kd : Qd;

  double acc[32];
  const double binit = (double)bias[e];
#pragma unroll
  for (int r = 0; r < 32; ++r) acc[r] = binit;

  for (int d = 0; d < BD; ++d) {
    const double wv = (double)W[d * BD + e];
#pragma unroll
    for (int r = 0; r < 32; ++r) acc[r] = fma(xs[r][d], wv, acc[r]);
  }

#pragma unroll
  for (int r = 0; r < 32; ++r) {
    const double a = acc[r];
    const long o = (row0 + r) * BD + e;
    Od[o] = a;
    if (isK) Khi[o] = f2bf((float)a);
  }
}

// ---------------- Screen v3: LDS-staged K + MFMA -> bf16 S matrix ----------------
// Grid 1024: (b, kq, rg) XCD-affine. Block = 8 waves; wave = (kt = w&3, qt = w>>2).
// Per step (kv chunk of 128): reg-prefetch next chunk, 8 chained 32x32x16 MFMAs from
// swizzled LDS, per-wave LDS transpose, coalesced bf16 store into S[row][col].
// C layout (m74/m101): col(lane&31)=q, row((reg&3)+8*(reg>>2)+4*(lane>>5))=kv-in-tile.
__global__ __launch_bounds__(512) void screen_kernel(
    const double* __restrict__ Qd, const unsigned short* __restrict__ Khi,
    unsigned short* __restrict__ Sbf) {
  __shared__ char kbuf[32768];     // 128 kv x 256B, XOR-swizzled 16B slots
  __shared__ char sbuf[8][2560];   // per-wave 32 rows x 80B transpose buffer

  const int tid = threadIdx.x;
  const int lane = tid & 63;
  const int w = tid >> 6;
  const int kt = w & 3, qt = w >> 2;
  const int c31 = lane & 31, hi = lane >> 5;

  const int blk = blockIdx.x;
  const int xcd = blk & 7;
  const int j = blk >> 3;
  const int combo = xcd * 2 + (j & 1);
  const int b = combo >> 2;
  const int kq = combo & 3;
  const int rg = j >> 1;
  const int rowbase = rg << 6;
  const int kvbase = kq << 10;

  const int qrow = qt * 32 + c31;
  const long grow = (long)b * BN + rowbase + qrow;

  bf16x8 bqf[8];
  {
    const double* qp = Qd + grow * BD + hi * 8;
#pragma unroll
    for (int ks = 0; ks < 8; ++ks) {
      bf16x8 pk;
#pragma unroll
      for (int jj = 0; jj < 8; ++jj) pk[jj] = (short)f2bf((float)qp[ks * 16 + jj]);
      bqf[ks] = pk;
    }
  }

  const char* kb = (const char*)(Khi + ((long)b * BN + kvbase) * BD);
  const int ar = kt * 32 + c31;
  const int ar256 = ar * 256;
  const int arx = ar & 15;

  char* my = sbuf[w];
  const int wr = c31 * 80;
  const long gq = (long)b * BN + rowbase + qt * 32 + (lane >> 1);
  unsigned short* dstbase = Sbf + gq * BN + kvbase + kt * 32 + (lane & 1) * 16;
  const char* rdp = my + (lane >> 1) * 80 + (lane & 1) * 32;

  uint4 stg[4];
#define LOADSTG(s)                                                \
  {                                                               \
    const char* gsrc_ = kb + (long)(s)*32768 + tid * 16;          \
    stg[0] = *(const uint4*)(gsrc_);                              \
    stg[1] = *(const uint4*)(gsrc_ + 8192);                       \
    stg[2] = *(const uint4*)(gsrc_ + 16384);                      \
    stg[3] = *(const uint4*)(gsrc_ + 24576);                      \
  }
#define WRITESTG()                                                \
  {                                                               \
    _Pragma("unroll") for (int j_ = 0; j_ < 4; ++j_) {            \
      const int L_ = j_ * 8192 + tid * 16;                        \
      const int r_ = L_ >> 8;                                     \
      const int c_ = (L_ >> 4) & 15;                              \
      *(uint4*)(kbuf + r_ * 256 + ((c_ ^ (r_ & 15)) << 4)) = stg[j_]; \
    }                                                             \
  }

  LOADSTG(0);
  WRITESTG();
  __syncthreads();

  for (int step = 0; step < 8; ++step) {
    if (step < 7) LOADSTG(step + 1);

    f32x16 acc = {0.f, 0.f, 0.f, 0.f, 0.f, 0.f, 0.f, 0.f,
                  0.f, 0.f, 0.f, 0.f, 0.f, 0.f, 0.f, 0.f};
#pragma unroll
    for (int ks = 0; ks < 8; ++ks) {
      const bf16x8 a = *(const bf16x8*)(kbuf + ar256 + (((ks * 2 + hi) ^ arx) << 4));
      acc = __builtin_amdgcn_mfma_f32_32x32x16_bf16(a, bqf[ks], acc, 0, 0, 0);
    }

    // pack 16 f32 -> bf16; wave-private transpose; coalesced store
#pragma unroll
    for (int p = 0; p < 4; ++p) {
      const unsigned int lo =
          (unsigned int)f2bf(acc[p * 4 + 0]) | ((unsigned int)f2bf(acc[p * 4 + 1]) << 16);
      const unsigned int hi2 =
          (unsigned int)f2bf(acc[p * 4 + 2]) | ((unsigned int)f2bf(acc[p * 4 + 3]) << 16);
      *(uint2*)(my + wr + p * 16 + hi * 8) = make_uint2(lo, hi2);
    }
    {
      const uint4 r0 = *(const uint4*)(rdp);
      const uint4 r1 = *(const uint4*)(rdp + 16);
      unsigned short* dst = dstbase + step * 128;
      *(uint4*)dst = r0;
      *(uint4*)(dst + 8) = r1;
    }

    __syncthreads();           // all MFMA/LDS reads of kbuf complete
    if (step < 7) WRITESTG();
    __syncthreads();           // kbuf ready for next step
  }
#undef LOADSTG
#undef WRITESTG
}

// ---------------- TopK v2: wave-per-row; rank-based selection, ballot emit ----------------
__device__ inline float rescore_f64(const double2* __restrict__ kp2, const double2* __restrict__ q2) {
  double a0 = 0.0, a1 = 0.0, a2 = 0.0, a3 = 0.0;
#pragma unroll
  for (int i = 0; i < 64; i += 4) {
    a0 = fma(q2[i + 0].y, kp2[i + 0].y, fma(q2[i + 0].x, kp2[i + 0].x, a0));
    a1 = fma(q2[i + 1].y, kp2[i + 1].y, fma(q2[i + 1].x, kp2[i + 1].x, a1));
    a2 = fma(q2[i + 2].y, kp2[i + 2].y, fma(q2[i + 2].x, kp2[i + 2].x, a2));
    a3 = fma(q2[i + 3].y, kp2[i + 3].y, fma(q2[i + 3].x, kp2[i + 3].x, a3));
  }
  return (float)(((a0 + a1) + (a2 + a3)) * 8.8388347648318447e-02);
}

__device__ inline unsigned int fmono(float v) {
  const unsigned int u = __float_as_uint(v);
  return (u & 0x80000000u) ? ~u : (u | 0x80000000u);
}
__device__ inline float fdemono(unsigned int k) {
  const unsigned int u = (k & 0x80000000u) ? (k & 0x7fffffffu) : ~k;
  return __uint_as_float(u);
}

// rec layout per row (48 u32): [0..19] prob(f32) by rank, [20..39] col(u32), [40] c0(f32)
__global__ __launch_bounds__(256) void topk_kernel(
    const double* __restrict__ Qd, const double* __restrict__ Kd,
    const unsigned short* __restrict__ Sbf, unsigned int* __restrict__ rec) {
  __shared__ unsigned short listL[4][CAND];

  const int tid = threadIdx.x;
  const int lane = tid & 63;
  const int w = tid >> 6;
  const int blk = blockIdx.x;
  const int b = (blk & 7) >> 1;                    // XCD-affinity: 2 XCDs per batch
  const int idx = ((blk >> 3) << 1) | (blk & 1);   // 0..1023
  const long row = (long)b * BN + idx * 4 + w;

  const unsigned short* srow = Sbf + row * BN;
  const unsigned long long lmask = (lane == 63) ? ~0ull >> 1 : (1ull << lane) - 1ull;

  // ---- pass A: load row scores into regs, per-lane max ----
  uint4 v[8];
  float pm[8];
#pragma unroll
  for (int i = 0; i < 8; ++i) {
    v[i] = *(const uint4*)(srow + i * 512 + lane * 8);
    float m0 = -3.4e38f;
#pragma unroll
    for (int k = 0; k < 4; ++k) {
      const unsigned int u = (&v[i].x)[k];
      m0 = fmaxf(m0, fmaxf(__uint_as_float(u << 16), __uint_as_float(u & 0xFFFF0000u)));
    }
    pm[i] = m0;
  }
  const float mymax = fmaxf(fmaxf(fmaxf(pm[0], pm[1]), fmaxf(pm[2], pm[3])),
                            fmaxf(fmaxf(pm[4], pm[5]), fmaxf(pm[6], pm[7])));

  // ---- tau via rank (independent shfl reads; tie-break by lane) ----
  int trank = 0;
  for (int j2 = 0; j2 < 64; ++j2) {
    const float ov = __shfl(mymax, j2);
    trank += (ov > mymax || (ov == mymax && j2 < lane)) ? 1 : 0;
  }
  const unsigned long long m19 = __ballot(trank == 19);
  const float tau = __shfl(mymax, (int)(__ffsll((long long)m19) - 1));
  const float th = tau - EPS_U;    // lower bound on row 20th minus margin

  // ---- pass B: ballot-prefix emit (deterministic, no atomics); c uniform ----
  unsigned int base = 0;
#pragma unroll
  for (int i = 0; i < 8; ++i) {
#pragma unroll
    for (int k = 0; k < 4; ++k) {
      const unsigned int u = (&v[i].x)[k];
      const float f0 = __uint_as_float(u << 16);
      const float f1 = __uint_as_float(u & 0xFFFF0000u);
      const int col0 = i * 512 + lane * 8 + k * 2;
      const unsigned long long b0 = __ballot(f0 >= th);
      if (f0 >= th) {
        const unsigned int p = base + (unsigned int)__popcll(b0 & lmask);
        if (p < CAND) listL[w][p] = (unsigned short)col0;
      }
      base += (unsigned int)__popcll(b0);
      const unsigned long long b1 = __ballot(f1 >= th);
      if (f1 >= th) {
        const unsigned int p = base + (unsigned int)__popcll(b1 & lmask);
        if (p < CAND) listL[w][p] = (unsigned short)(col0 + 1);
      }
      base += (unsigned int)__popcll(b1);
    }
  }
  const int c = (int)min(base, (unsigned int)CAND);

  // ---- exact f64 rescore -> packed keys: (mono(val) << 12) | (4095 - col) ----
  const double2* q2 = (const double2*)(Qd + row * BD);
  const double* kbd = Kd + (long)b * BN * BD;

  unsigned long long key0 = 0ull, key1 = 0ull;
  if (lane < c) {
    const int kv = (int)listL[w][lane];
    const float vv = rescore_f64((const double2*)(kbd + (long)kv * BD), q2);
    key0 = ((unsigned long long)fmono(vv) << 12) | (unsigned int)(4095 - kv);
  }
  if (lane + 64 < c) {
    const int kv = (int)listL[w][lane + 64];
    const float vv = rescore_f64((const double2*)(kbd + (long)kv * BD), q2);
    key1 = ((unsigned long long)fmono(vv) << 12) | (unsigned int)(4095 - kv);
  }

  unsigned int* rr = rec + row * 48;

  if (c <= 64) {
    // ---- rank-based top-20: keys unique (col bits); krank<20 lanes are the winners ----
    int krank = 0;
    for (int j2 = 0; j2 < 64; ++j2) {
      const unsigned long long ok = __shfl(key0, j2);
      krank += (ok > key0) ? 1 : 0;
    }
    const unsigned long long mm = __ballot(krank == 0);
    const unsigned long long mkey = __shfl(key0, (int)(__ffsll((long long)mm) - 1));
    const float m = fmaxf(fdemono((unsigned int)(mkey >> 12)), 0.0f);

    const float val = fdemono((unsigned int)(key0 >> 12));
    const float e = (krank < TOPK) ? expf(val - m) : 0.0f;
    float se = e;
#pragma unroll
    for (int off = 32; off; off >>= 1) se += __shfl_xor(se, off);
    const float Z = se + (float)(BN - TOPK) * expf(-m);
    if (krank < TOPK) {
      rr[krank] = __float_as_uint(e / Z);
      rr[20 + krank] = (unsigned int)(4095 - (int)(key0 & 0xFFFull));
    }
    if (lane == 0) rr[40] = __float_as_uint(expf(-m) / Z);
  } else {
    // ---- rare fallback (c>64): iterative 20-step extraction ----
    if (key1 > key0) { const unsigned long long t = key0; key0 = key1; key1 = t; }
    float m = 0.0f, se = 0.0f;
    float myval = 0.0f;
    int mycol = 0;
    for (int it = 0; it < TOPK; ++it) {
      unsigned long long rk = key0;
      for (int off = 32; off; off >>= 1) {
        const unsigned long long ok = __shfl_xor(rk, off);
        rk = (ok > rk) ? ok : rk;
      }
      const float rv = fdemono((unsigned int)(rk >> 12));
      if (it == 0) m = fmaxf(rv, 0.0f);
      se += expf(rv - m);
      if (lane == it) { myval = rv; mycol = 4095 - (int)(rk & 0xFFFull); }
      if (key0 == rk) { key0 = key1; key1 = 0ull; }
    }
    const float Z = se + (float)(BN - TOPK) * expf(-m);
    if (lane < TOPK) {
      rr[lane] = __float_as_uint(expf(myval - m) / Z);
      rr[20 + lane] = (unsigned int)mycol;
    }
    if (lane == 0) rr[40] = __float_as_uint(expf(-m) / Z);
  }
}

// ---------------- Fill: one row per block, stream + LDS-bitmap patch (R8/R10, passed) ----------------
__global__ __launch_bounds__(256) void fill_kernel(
    const unsigned int* __restrict__ rec, float* __restrict__ out) {
  __shared__ unsigned int bm[128];
  __shared__ float pv[TOPK];
  __shared__ int pc[TOPK];
  __shared__ float sc0;

  const int tid = threadIdx.x;
  const long row = blockIdx.x;
  const unsigned int* rr = rec + row * 48;

  if (tid < 128) bm[tid] = 0;
  __syncthreads();
  if (tid < TOPK) {
    pv[tid] = __uint_as_float(rr[tid]);
    const int col = (int)rr[20 + tid];
    pc[tid] = col;
    atomicOr(&bm[col >> 5], 1u << (col & 31));
  }
  if (tid == TOPK) sc0 = __uint_as_float(rr[40]);
  __syncthreads();

  const float c0 = sc0;
  const float4 cv = make_float4(c0, c0, c0, c0);
  float4* op = (float4*)(out + row * BN);

#pragma unroll
  for (int k = 0; k < 4; ++k) {
    const int j = tid + k * 256;
    const unsigned int bits = (bm[j >> 3] >> ((j & 7) * 4)) & 0xFu;
    if (bits == 0u) {
      op[j] = cv;
    } else {
      float4 v = cv;
      const int col0 = j * 4;
#pragma unroll
      for (int cmp = 0; cmp < 4; ++cmp) {
        if ((bits >> cmp) & 1u) {
          const int col = col0 + cmp;
          float pvv = c0;
          for (int i = 0; i < TOPK; ++i)
            if (pc[i] == col) pvv = pv[i];
          (&v.x)[cmp] = pvv;
        }
      }
      op[j] = v;
    }
  }
}

extern "C" void kernel_launch(void* const* d_in, const int* in_sizes, int n_in,
                              void* d_out, int out_size, void* d_ws, size_t ws_size,
                              hipStream_t stream) {
  const float* x  = (const float*)d_in[0];
  const float* Wq = (const float*)d_in[1];
  const float* bq = (const float*)d_in[2];
  const float* Wk = (const float*)d_in[3];
  const float* bk = (const float*)d_in[4];
  float* out = (float*)d_out;

  const long NE = (long)NB * BN * BD;  // 2,097,152 elements
  const long NR = (long)NB * BN;       // 16384 rows
  double* Qd = (double*)d_ws;                          // 16 MB
  double* Kd = Qd + NE;                                // 16 MB
  unsigned short* Khi = (unsigned short*)(Kd + NE);    // 4 MB
  unsigned short* Sbf = Khi + NE;                      // 134 MB (16384 x 4096 bf16)
  unsigned int* rec = (unsigned int*)(Sbf + NR * BN);  // 3 MB (NR x 48 u32)

  proj_kernel<<<NB * BN / 32, 256, 0, stream>>>(x, Wq, bq, Wk, bk, Qd, Kd, Khi);
  screen_kernel<<<1024, 512, 0, stream>>>(Qd, Khi, Sbf);
  topk_kernel<<<NR / 4, 256, 0, stream>>>(Qd, Kd, Sbf, rec);
  fill_kernel<<<NR, 256, 0, stream>>>(rec, out);
}

// Round 12
// 322.777 us; speedup vs baseline: 1.0675x; 1.0675x over previous
//
#include <hip/hip_runtime.h>

#define BN 4096
#define BD 128
#define NB 4
#define TOPK 20
#define CAND 96
#define EPS_U 0.9f              // unscaled-score margin (covers MFMA + bf16 rounding, >=11 sigma)

typedef float f32x16 __attribute__((ext_vector_type(16)));
typedef short bf16x8 __attribute__((ext_vector_type(8)));

__device__ inline unsigned short f2bf(float f) {
  unsigned int u = __float_as_uint(f);
  unsigned int r = (u + 0x7FFFu + ((u >> 16) & 1u)) >> 16;
  return (unsigned short)r;
}

// ---------------- Projection (f64 accumulate) -> Qd, Kd (f64) + Khi (bf16) ----------------
__global__ __launch_bounds__(256) void proj_kernel(
    const float* __restrict__ x,
    const float* __restrict__ Wq, const float* __restrict__ bq,
    const float* __restrict__ Wk, const float* __restrict__ bk,
    double* __restrict__ Qd, double* __restrict__ Kd, unsigned short* __restrict__ Khi) {
  __shared__ double xs[32][129];
  const int tid = threadIdx.x;
  const long row0 = (long)blockIdx.x * 32;
  const float* xsrc = x + row0 * BD;
  for (int i = tid; i < 32 * BD; i += 256) xs[i >> 7][i & 127] = (double)xsrc[i];
  __syncthreads();

  const int e = tid & 127;
  const bool isK = tid >= 128;
  const float* W = isK ? Wk : Wq;
  const float* bias = isK ? bk : bq;
  double* Od = isK ? Kd : Qd;

  double acc[32];
  const double binit = (double)bias[e];
#pragma unroll
  for (int r = 0; r < 32; ++r) acc[r] = binit;

  for (int d = 0; d < BD; ++d) {
    const double wv = (double)W[d * BD + e];
#pragma unroll
    for (int r = 0; r < 32; ++r) acc[r] = fma(xs[r][d], wv, acc[r]);
  }

#pragma unroll
  for (int r = 0; r < 32; ++r) {
    const double a = acc[r];
    const long o = (row0 + r) * BD + e;
    Od[o] = a;
    if (isK) Khi[o] = f2bf((float)a);
  }
}

// ---------------- helpers ----------------
__device__ inline float rescore_f64(const double2* __restrict__ kp2, const double2* __restrict__ q2) {
  double a0 = 0.0, a1 = 0.0, a2 = 0.0, a3 = 0.0;
#pragma unroll
  for (int i = 0; i < 64; i += 4) {
    a0 = fma(q2[i + 0].y, kp2[i + 0].y, fma(q2[i + 0].x, kp2[i + 0].x, a0));
    a1 = fma(q2[i + 1].y, kp2[i + 1].y, fma(q2[i + 1].x, kp2[i + 1].x, a1));
    a2 = fma(q2[i + 2].y, kp2[i + 2].y, fma(q2[i + 2].x, kp2[i + 2].x, a2));
    a3 = fma(q2[i + 3].y, kp2[i + 3].y, fma(q2[i + 3].x, kp2[i + 3].x, a3));
  }
  return (float)(((a0 + a1) + (a2 + a3)) * 8.8388347648318447e-02);
}

__device__ inline unsigned int fmono(float v) {
  const unsigned int u = __float_as_uint(v);
  return (u & 0x80000000u) ? ~u : (u | 0x80000000u);
}
__device__ inline float fdemono(unsigned int k) {
  const unsigned int u = (k & 0x80000000u) ? (k & 0x7fffffffu) : ~k;
  return __uint_as_float(u);
}

// ---------------- Fused: MFMA scores + pool + tau + emit + rescore + top-20 ----------------
// Grid 512 (XCD-affine: b = (blk&7)>>1): block = 32 q-rows x full 4096 kv, 8 waves.
// Wave w owns kv-eighth [w*512, w*512+512): 16 tiles x 8 chained 32x32x16 MFMAs,
// per-lane top-2 pool (2 lanes/row/wave -> 32 pooled/row), transpose-store S (block-local
// scratch in global; re-read is same-XCD L2-hot). tau = 20th of pool (bitonic-32).
// Then wave w owns rows [w*4, w*4+4): ballot emit >= tau-EPS, f64 rescore, bitonic-64
// key sort (jax (val desc, col asc) tie-break), write per-row rec.
// C layout (m74/m101): col(lane&31)=q, row((reg&3)+8*(reg>>2)+4*(lane>>5))=kv-in-tile.
__global__ __launch_bounds__(512) void fused_kernel(
    const double* __restrict__ Qd, const double* __restrict__ Kd,
    const unsigned short* __restrict__ Khi,
    unsigned short* __restrict__ Sbf, unsigned int* __restrict__ rec) {
  __shared__ char sbuf[8][2560];      // per-wave 32 rows x 80B transpose buffer
  __shared__ float pool[32][32];      // per-row pooled top-2s (bf16-truncated)
  __shared__ float tauL[32];
  __shared__ unsigned short listL[8][CAND];

  const int tid = threadIdx.x;
  const int lane = tid & 63;
  const int w = tid >> 6;
  const int c31 = lane & 31, hi = lane >> 5;

  const int blk = blockIdx.x;
  const int b = (blk & 7) >> 1;                    // XCD-affinity: 2 XCDs per batch
  const int rg = ((blk >> 3) << 1) | (blk & 1);    // 0..127
  const int rowbase = rg << 5;                     // 32 rows per block

  // Q B-fragments for this block's single 32-row q-tile
  bf16x8 bqf[8];
  {
    const double* qp = Qd + ((long)b * BN + rowbase + c31) * BD + hi * 8;
#pragma unroll
    for (int ks = 0; ks < 8; ++ks) {
      bf16x8 pk;
#pragma unroll
      for (int jj = 0; jj < 8; ++jj) pk[jj] = (short)f2bf((float)qp[ks * 16 + jj]);
      bqf[ks] = pk;
    }
  }

  // A-frag base: kv row = w*512 + t*32 + c31
  const unsigned short* kb = Khi + ((long)b * BN + w * 512 + c31) * BD + hi * 8;

  char* my = sbuf[w];
  const int wr = c31 * 80;
  unsigned short* dstbase = Sbf + ((long)b * BN + rowbase + (lane >> 1)) * BN
                            + w * 512 + (lane & 1) * 16;
  const char* rdp = my + (lane >> 1) * 80 + (lane & 1) * 32;

  float t1 = -3.4e38f, t2 = -3.4e38f;

  // ---- phase 1: MFMA + pool + S store ----
  for (int t = 0; t < 16; ++t) {
    const unsigned short* kr = kb + (long)t * 32 * BD;
    f32x16 acc = {0.f, 0.f, 0.f, 0.f, 0.f, 0.f, 0.f, 0.f,
                  0.f, 0.f, 0.f, 0.f, 0.f, 0.f, 0.f, 0.f};
#pragma unroll
    for (int ks = 0; ks < 8; ++ks) {
      const bf16x8 a = *(const bf16x8*)(kr + ks * 16);
      acc = __builtin_amdgcn_mfma_f32_32x32x16_bf16(a, bqf[ks], acc, 0, 0, 0);
    }
#pragma unroll
    for (int reg = 0; reg < 16; ++reg) {
      const float s = acc[reg];
      const float w1 = fmaxf(t1, s);
      t2 = fmaxf(t2, fminf(t1, s));
      t1 = w1;
    }
    // pack -> wave-private transpose -> global S (proven R9/R10 path)
#pragma unroll
    for (int p = 0; p < 4; ++p) {
      const unsigned int lo =
          (unsigned int)f2bf(acc[p * 4 + 0]) | ((unsigned int)f2bf(acc[p * 4 + 1]) << 16);
      const unsigned int hi2 =
          (unsigned int)f2bf(acc[p * 4 + 2]) | ((unsigned int)f2bf(acc[p * 4 + 3]) << 16);
      *(uint2*)(my + wr + p * 16 + hi * 8) = make_uint2(lo, hi2);
    }
    const uint4 r0 = *(const uint4*)(rdp);
    const uint4 r1 = *(const uint4*)(rdp + 16);
    unsigned short* dst = dstbase + t * 32;
    *(uint4*)dst = r0;
    *(uint4*)(dst + 8) = r1;
  }

  // pool (truncate to bf16: positive top values only get lowered -> tau stays a lower bound)
  pool[c31][(w * 2 + hi) * 2 + 0] = __uint_as_float(__float_as_uint(t1) & 0xFFFF0000u);
  pool[c31][(w * 2 + hi) * 2 + 1] = __uint_as_float(__float_as_uint(t2) & 0xFFFF0000u);
  __syncthreads();   // drains vmcnt -> S visible block-wide; pool visible

  // ---- phase 2: tau per row = 20th largest of 32 pooled (bitonic-32 per half-wave) ----
#pragma unroll
  for (int p = 0; p < 2; ++p) {
    const int row = w * 4 + p * 2 + hi;
    float v = pool[row][c31];
#pragma unroll
    for (int k = 2; k <= 32; k <<= 1) {
#pragma unroll
      for (int jj = k >> 1; jj > 0; jj >>= 1) {
        const float o = __shfl_xor(v, jj);
        const bool keepmin = (((c31 & k) == 0) == ((c31 & jj) == 0));
        v = keepmin ? fminf(v, o) : fmaxf(v, o);
      }
    }
    if (c31 == 12) tauL[row] = v - EPS_U;   // ascending idx 12 = 20th largest of 32
  }
  __syncthreads();

  // ---- phase 3: per-wave rows: emit + rescore + top-20 ----
  const unsigned long long lmask = (lane == 63) ? ~0ull >> 1 : (1ull << lane) - 1ull;
  const double* kbd = Kd + (long)b * BN * BD;

  for (int rr2 = 0; rr2 < 4; ++rr2) {
    const int row = w * 4 + rr2;
    const long grow = (long)b * BN + rowbase + row;
    const unsigned short* srow = Sbf + grow * BN;
    const float th = tauL[row];

    uint4 v[8];
#pragma unroll
    for (int i = 0; i < 8; ++i) v[i] = *(const uint4*)(srow + i * 512 + lane * 8);

    // ballot-prefix emit (deterministic, no atomics)
    unsigned int base = 0;
#pragma unroll
    for (int i = 0; i < 8; ++i) {
#pragma unroll
      for (int k = 0; k < 4; ++k) {
        const unsigned int u = (&v[i].x)[k];
        const float f0 = __uint_as_float(u << 16);
        const float f1 = __uint_as_float(u & 0xFFFF0000u);
        const int col0 = i * 512 + lane * 8 + k * 2;
        const unsigned long long b0 = __ballot(f0 >= th);
        if (f0 >= th) {
          const unsigned int p = base + (unsigned int)__popcll(b0 & lmask);
          if (p < CAND) listL[w][p] = (unsigned short)col0;
        }
        base += (unsigned int)__popcll(b0);
        const unsigned long long b1 = __ballot(f1 >= th);
        if (f1 >= th) {
          const unsigned int p = base + (unsigned int)__popcll(b1 & lmask);
          if (p < CAND) listL[w][p] = (unsigned short)(col0 + 1);
        }
        base += (unsigned int)__popcll(b1);
      }
    }
    const int c = (int)min(base, (unsigned int)CAND);

    // exact f64 rescore -> packed keys: (mono(val) << 12) | (4095 - col)
    const double2* q2 = (const double2*)(Qd + grow * BD);
    unsigned long long key0 = 0ull, key1 = 0ull;
    if (lane < c) {
      const int kv = (int)listL[w][lane];
      const float vv = rescore_f64((const double2*)(kbd + (long)kv * BD), q2);
      key0 = ((unsigned long long)fmono(vv) << 12) | (unsigned int)(4095 - kv);
    }
    if (lane + 64 < c) {
      const int kv = (int)listL[w][lane + 64];
      const float vv = rescore_f64((const double2*)(kbd + (long)kv * BD), q2);
      key1 = ((unsigned long long)fmono(vv) << 12) | (unsigned int)(4095 - kv);
    }

    unsigned int* rr = rec + grow * 48;

    if (c <= 64) {
      // bitonic-64 ascending key sort; top-20 in lanes 44..63 (R10, proven)
      unsigned long long kk = key0;
#pragma unroll
      for (int k = 2; k <= 64; k <<= 1) {
#pragma unroll
        for (int jj = k >> 1; jj > 0; jj >>= 1) {
          const unsigned long long o = __shfl_xor(kk, jj);
          const bool keepmin = (((lane & k) == 0) == ((lane & jj) == 0));
          kk = keepmin ? (o < kk ? o : kk) : (o > kk ? o : kk);
        }
      }
      const unsigned long long ktop = __shfl(kk, 63);
      const float m = fmaxf(fdemono((unsigned int)(ktop >> 12)), 0.0f);
      const float val = fdemono((unsigned int)(kk >> 12));
      const int col = 4095 - (int)(kk & 0xFFFull);
      const float e = (lane >= 44) ? expf(val - m) : 0.0f;
      float se = e;
#pragma unroll
      for (int off = 32; off; off >>= 1) se += __shfl_xor(se, off);
      const float Z = se + (float)(BN - TOPK) * expf(-m);
      if (lane >= 44) {
        const int r = 63 - lane;
        rr[r] = __float_as_uint(e / Z);
        rr[20 + r] = (unsigned int)col;
      }
      if (lane == 0) rr[40] = __float_as_uint(expf(-m) / Z);
    } else {
      // rare fallback (c>64): iterative 20-step extraction
      if (key1 > key0) { const unsigned long long t = key0; key0 = key1; key1 = t; }
      float m = 0.0f, se = 0.0f;
      float myval = 0.0f;
      int mycol = 0;
      for (int it = 0; it < TOPK; ++it) {
        unsigned long long rk = key0;
        for (int off = 32; off; off >>= 1) {
          const unsigned long long ok = __shfl_xor(rk, off);
          rk = (ok > rk) ? ok : rk;
        }
        const float rv = fdemono((unsigned int)(rk >> 12));
        if (it == 0) m = fmaxf(rv, 0.0f);
        se += expf(rv - m);
        if (lane == it) { myval = rv; mycol = 4095 - (int)(rk & 0xFFFull); }
        if (key0 == rk) { key0 = key1; key1 = 0ull; }
      }
      const float Z = se + (float)(BN - TOPK) * expf(-m);
      if (lane < TOPK) {
        rr[lane] = __float_as_uint(expf(myval - m) / Z);
        rr[20 + lane] = (unsigned int)mycol;
      }
      if (lane == 0) rr[40] = __float_as_uint(expf(-m) / Z);
    }
  }
}

// ---------------- Fill: one row per block, stream + LDS-bitmap patch (R8/R10, passed) ----------------
__global__ __launch_bounds__(256) void fill_kernel(
    const unsigned int* __restrict__ rec, float* __restrict__ out) {
  __shared__ unsigned int bm[128];
  __shared__ float pv[TOPK];
  __shared__ int pc[TOPK];
  __shared__ float sc0;

  const int tid = threadIdx.x;
  const long row = blockIdx.x;
  const unsigned int* rr = rec + row * 48;

  if (tid < 128) bm[tid] = 0;
  __syncthreads();
  if (tid < TOPK) {
    pv[tid] = __uint_as_float(rr[tid]);
    const int col = (int)rr[20 + tid];
    pc[tid] = col;
    atomicOr(&bm[col >> 5], 1u << (col & 31));
  }
  if (tid == TOPK) sc0 = __uint_as_float(rr[40]);
  __syncthreads();

  const float c0 = sc0;
  const float4 cv = make_float4(c0, c0, c0, c0);
  float4* op = (float4*)(out + row * BN);

#pragma unroll
  for (int k = 0; k < 4; ++k) {
    const int j = tid + k * 256;
    const unsigned int bits = (bm[j >> 3] >> ((j & 7) * 4)) & 0xFu;
    if (bits == 0u) {
      op[j] = cv;
    } else {
      float4 v = cv;
      const int col0 = j * 4;
#pragma unroll
      for (int cmp = 0; cmp < 4; ++cmp) {
        if ((bits >> cmp) & 1u) {
          const int col = col0 + cmp;
          float pvv = c0;
          for (int i = 0; i < TOPK; ++i)
            if (pc[i] == col) pvv = pv[i];
          (&v.x)[cmp] = pvv;
        }
      }
      op[j] = v;
    }
  }
}

extern "C" void kernel_launch(void* const* d_in, const int* in_sizes, int n_in,
                              void* d_out, int out_size, void* d_ws, size_t ws_size,
                              hipStream_t stream) {
  const float* x  = (const float*)d_in[0];
  const float* Wq = (const float*)d_in[1];
  const float* bq = (const float*)d_in[2];
  const float* Wk = (const float*)d_in[3];
  const float* bk = (const float*)d_in[4];
  float* out = (float*)d_out;

  const long NE = (long)NB * BN * BD;  // 2,097,152 elements
  const long NR = (long)NB * BN;       // 16384 rows
  double* Qd = (double*)d_ws;                          // 16 MB
  double* Kd = Qd + NE;                                // 16 MB
  unsigned short* Khi = (unsigned short*)(Kd + NE);    // 4 MB
  unsigned short* Sbf = Khi + NE;                      // 134 MB (block-local scratch)
  unsigned int* rec = (unsigned int*)(Sbf + NR * BN);  // 3 MB (NR x 48 u32)

  proj_kernel<<<NB * BN / 32, 256, 0, stream>>>(x, Wq, bq, Wk, bk, Qd, Kd, Khi);
  fused_kernel<<<512, 512, 0, stream>>>(Qd, Kd, Khi, Sbf, rec);
  fill_kernel<<<NR, 256, 0, stream>>>(rec, out);
}